// Round 10
// baseline (511.719 us; speedup 1.0000x reference)
//
#include <hip/hip_runtime.h>
#include <hip/hip_bf16.h>
#include <stdint.h>

// ---------- types ----------
typedef __attribute__((ext_vector_type(8))) short bf16x8;     // 8 bf16 (4 VGPRs) MFMA frag
typedef __attribute__((ext_vector_type(4))) float f32x4;      // MFMA accum
typedef __attribute__((ext_vector_type(4))) unsigned short u16x4;
typedef __attribute__((ext_vector_type(4))) float float4v;

#define MFMA16(a, b, c) __builtin_amdgcn_mfma_f32_16x16x32_bf16((a), (b), (c), 0, 0, 0)

// Native f32->bf16 (RTNE); pairs lower to v_cvt_pk_bf16_f32 on gfx950.
__device__ __forceinline__ unsigned short f2bf(float f) {
  return __builtin_bit_cast(unsigned short, (__bf16)f);
}
__device__ __forceinline__ float m3(float a, float b, float c) {
  return fmaxf(fmaxf(a, b), c);                 // clang fuses to v_max3_f32
}

typedef const __attribute__((address_space(1))) void* gptr1_t;
typedef __attribute__((address_space(3))) void* lptr3_t;
__device__ __forceinline__ void gload16(const void* g, void* l) {
  // HW semantics: LDS dest = wave-uniform base + lane*16; global src per-lane.
  __builtin_amdgcn_global_load_lds((gptr1_t)g, (lptr3_t)l, 16, 0, 0);
}

// ---------- 1) x fp32 -> bf16 ----------
__global__ __launch_bounds__(256) void cvt_x_kernel(const float* __restrict__ in,
                                                    unsigned short* __restrict__ out) {
  int i = blockIdx.x * 256 + threadIdx.x;          // exactly n/4 threads launched
  float4v f = ((const float4v*)in)[i];
  u16x4 o;
  o[0] = f2bf(f[0]); o[1] = f2bf(f[1]); o[2] = f2bf(f[2]); o[3] = f2bf(f[3]);
  ((u16x4*)out)[i] = o;
}

// ---------- 2) weight fp32 [K][N] -> bf16 transposed [N][K] ----------
__global__ __launch_bounds__(256) void wt_cvt_kernel(const float* __restrict__ w0,
                                                     const float* __restrict__ w1,
                                                     const float* __restrict__ w2,
                                                     const float* __restrict__ w3,
                                                     unsigned short* __restrict__ out) {
  const float* in = blockIdx.z == 0 ? w0 : blockIdx.z == 1 ? w1 : blockIdx.z == 2 ? w2 : w3;
  unsigned short* o = out + (size_t)blockIdx.z * 1024 * 1024;
  __shared__ float tile[32][33];
  int tx = threadIdx.x & 31, ty = threadIdx.x >> 5;          // 32 x 8
  int c0 = blockIdx.x * 32, r0 = blockIdx.y * 32;
#pragma unroll
  for (int i = 0; i < 4; i++)
    tile[ty + 8 * i][tx] = in[(size_t)(r0 + ty + 8 * i) * 1024 + c0 + tx];
  __syncthreads();
#pragma unroll
  for (int i = 0; i < 4; i++)
    o[(size_t)(c0 + ty + 8 * i) * 1024 + r0 + tx] = f2bf(tile[tx][ty + 8 * i]);
}

// ---------- 3) GEMM 128x128, BK=32 (m97 structure): C = A[M][1024](bf16) @ W ----------
template <bool OUTF32>
__global__ __launch_bounds__(256) void gemm128_kernel(
    const unsigned short* __restrict__ A,
    const unsigned short* __restrict__ B0, const unsigned short* __restrict__ B1,
    const unsigned short* __restrict__ B2,
    void* C0, void* C1, void* C2) {
  constexpr int K = 1024, N = 1024;
  const unsigned short* Bt = blockIdx.z == 0 ? B0 : blockIdx.z == 1 ? B1 : B2;
  void* Cv = blockIdx.z == 0 ? C0 : blockIdx.z == 1 ? C1 : C2;

  __shared__ unsigned short As[128 * 32];
  __shared__ unsigned short Bs[128 * 32];

  const int tid = threadIdx.x;
  const int w = tid >> 6, lane = tid & 63, l15 = lane & 15, l4 = lane >> 4;
  const int wm = w >> 1, wn = w & 1;
  const int m0 = blockIdx.x * 128, n0 = blockIdx.y * 128;

  f32x4 acc[4][4] = {};

  const int srow = w * 32 + (lane >> 2);     // staging row (inst i adds 16)
  const int scol = (lane & 3) * 8;           // bf16 col within BK
  const unsigned short* ga = A + (size_t)(m0 + srow) * K + scol;
  const unsigned short* gb = Bt + (size_t)(n0 + srow) * K + scol;
  char* lA = (char*)As + w * 2048;           // + i*1024 ; HW adds lane*16
  char* lB = (char*)Bs + w * 2048;

  for (int k0 = 0; k0 < K; k0 += 32) {
    __syncthreads();
    gload16(ga + k0, lA);
    gload16(ga + k0 + 16 * K, lA + 1024);
    gload16(gb + k0, lB);
    gload16(gb + k0 + 16 * K, lB + 1024);
    __syncthreads();

    bf16x8 af[4], bfr[4];
#pragma unroll
    for (int mi = 0; mi < 4; mi++)
      af[mi] = *(const bf16x8*)&As[(wm * 64 + mi * 16 + l15) * 32 + 8 * l4];
#pragma unroll
    for (int ni = 0; ni < 4; ni++)
      bfr[ni] = *(const bf16x8*)&Bs[(wn * 64 + ni * 16 + l15) * 32 + 8 * l4];
#pragma unroll
    for (int mi = 0; mi < 4; mi++)
#pragma unroll
      for (int ni = 0; ni < 4; ni++)
        acc[mi][ni] = MFMA16(af[mi], bfr[ni], acc[mi][ni]);
  }

#pragma unroll
  for (int mi = 0; mi < 4; mi++)
#pragma unroll
    for (int ni = 0; ni < 4; ni++)
#pragma unroll
      for (int r = 0; r < 4; r++) {
        int mg = m0 + wm * 64 + mi * 16 + 4 * l4 + r;
        int ng = n0 + wn * 64 + ni * 16 + l15;
        if (OUTF32)
          ((float*)Cv)[(size_t)mg * N + ng] = acc[mi][ni][r];
        else
          ((unsigned short*)Cv)[(size_t)mg * N + ng] = f2bf(acc[mi][ni][r]);
      }
}

// ---------- 3b) GEMM 64x128 f32-out: out-projection (1024 blocks = 4/CU) ----------
__global__ __launch_bounds__(256) void gemm64_kernel(const unsigned short* __restrict__ A,
                                                     const unsigned short* __restrict__ Bt,
                                                     float* __restrict__ Cv) {
  constexpr int K = 1024, N = 1024;
  __shared__ unsigned short As[64 * 32];
  __shared__ unsigned short Bs[128 * 32];

  const int tid = threadIdx.x;
  const int w = tid >> 6, lane = tid & 63, l15 = lane & 15, l4 = lane >> 4;
  const int wm = w >> 1, wn = w & 1;                // wave tile 32x64
  const int m0 = blockIdx.x * 64, n0 = blockIdx.y * 128;

  f32x4 acc[2][4] = {};

  const int arow = w * 16 + (lane >> 2);            // A staging: 16 rows/wave
  const int brow = w * 32 + (lane >> 2);            // B staging: 32 rows/wave (2 insts)
  const int scol = (lane & 3) * 8;
  const unsigned short* ga = A + (size_t)(m0 + arow) * K + scol;
  const unsigned short* gb = Bt + (size_t)(n0 + brow) * K + scol;
  char* lA = (char*)As + w * 1024;
  char* lB = (char*)Bs + w * 2048;

  for (int k0 = 0; k0 < K; k0 += 32) {
    __syncthreads();
    gload16(ga + k0, lA);
    gload16(gb + k0, lB);
    gload16(gb + k0 + 16 * K, lB + 1024);
    __syncthreads();

    bf16x8 af[2], bfr[4];
#pragma unroll
    for (int mi = 0; mi < 2; mi++)
      af[mi] = *(const bf16x8*)&As[(wm * 32 + mi * 16 + l15) * 32 + 8 * l4];
#pragma unroll
    for (int ni = 0; ni < 4; ni++)
      bfr[ni] = *(const bf16x8*)&Bs[(wn * 64 + ni * 16 + l15) * 32 + 8 * l4];
#pragma unroll
    for (int mi = 0; mi < 2; mi++)
#pragma unroll
      for (int ni = 0; ni < 4; ni++)
        acc[mi][ni] = MFMA16(af[mi], bfr[ni], acc[mi][ni]);
  }

#pragma unroll
  for (int mi = 0; mi < 2; mi++)
#pragma unroll
    for (int ni = 0; ni < 4; ni++)
#pragma unroll
      for (int r = 0; r < 4; r++) {
        int mg = m0 + wm * 32 + mi * 16 + 4 * l4 + r;
        int ng = n0 + wn * 64 + ni * 16 + l15;
        Cv[(size_t)mg * N + ng] = acc[mi][ni][r];
      }
}

// ---------- 4) causal flash attention ----------
// R5 structure (76us verified) + shared-V PV graft, implemented to satisfy the
// spill rules learned in R4/R6/R7/R8:
//   - sequencing QK_A->SMAX_A->QK_B->SMAX_B->PV(fused): sA and sB NEVER co-live;
//     only pA0/pA1 (+8 regs) cross a softmax phase.
//   - all compute is inline macros assigning NAMED locals; no array or reference
//     out-param crosses any lambda/function boundary.
//   - launch_bounds(256,4): <=128 VGPR costs nothing (LDS caps at 4 blocks/CU and
//     waves/SIMD only halve past 128 regs).
// Overlap iterations save 8 V ds_read_b128 per wave (each V frag feeds both streams).
// Rest = R5: flat grid 1024 XCD-chunked, paired q-tiles (p,31-p), dbuf K/Vt,
// one barrier/tile, ones-MFMA l-sum, defer-max, max3 tree.

#define QK_S(SUB, QF0, QF1, SD)                                                   \
  {                                                                               \
    const bf16x8 k0_ = *(const bf16x8*)&Kc[((SUB)*16 + l15) * 64 + ((8 * l4) ^ sw)]; \
    const bf16x8 k1_ = *(const bf16x8*)&Kc[((SUB)*16 + l15) * 64 + ((32 + 8 * l4) ^ sw)]; \
    f32x4 z_ = {0.f, 0.f, 0.f, 0.f};                                              \
    z_ = MFMA16(k0_, QF0, z_);                                                    \
    z_ = MFMA16(k1_, QF1, z_);                                                    \
    SD = z_;                                                                      \
  }

// softmax: mask(diag) + max3 tree + 2 shfl reduce + defer-max rescale + exp2 +
// P store (4x b64) + P frag reload (2x b128). All state in named scalars.
#define SMAX(S0, S1, S2, S3, MR, OACC, LACC, DIAG, PF0, PF1)                      \
  {                                                                               \
    if (DIAG) {                                                                   \
      _Pragma("unroll") for (int r4 = 0; r4 < 4; r4++) {                          \
        if ( 0 + 4 * l4 + r4 > qq) S0[r4] = -__builtin_inff();                    \
        if (16 + 4 * l4 + r4 > qq) S1[r4] = -__builtin_inff();                    \
        if (32 + 4 * l4 + r4 > qq) S2[r4] = -__builtin_inff();                    \
        if (48 + 4 * l4 + r4 > qq) S3[r4] = -__builtin_inff();                    \
      }                                                                           \
    }                                                                             \
    const float t0_ = m3(S0[0], S0[1], S0[2]);                                    \
    const float t1_ = m3(S0[3], S1[0], S1[1]);                                    \
    const float t2_ = m3(S1[2], S1[3], S2[0]);                                    \
    const float t3_ = m3(S2[1], S2[2], S2[3]);                                    \
    const float t4_ = m3(S3[0], S3[1], S3[2]);                                    \
    float mt_ = fmaxf(m3(t0_, t1_, t2_), m3(t3_, t4_, S3[3]));                    \
    mt_ = fmaxf(mt_, __shfl_xor(mt_, 16));                                        \
    mt_ = fmaxf(mt_, __shfl_xor(mt_, 32));                                        \
    if (!__all(mt_ <= MR + 44.3614f)) {                                           \
      const float mn_ = fmaxf(MR, mt_);                                           \
      const float al_ = __builtin_amdgcn_exp2f((MR - mn_) * C);                   \
      const float a0_ = __shfl(al_, 4 * l4 + 0);                                  \
      const float a1_ = __shfl(al_, 4 * l4 + 1);                                  \
      const float a2_ = __shfl(al_, 4 * l4 + 2);                                  \
      const float a3_ = __shfl(al_, 4 * l4 + 3);                                  \
      _Pragma("unroll") for (int d_ = 0; d_ < 4; ++d_) {                          \
        OACC[d_][0] *= a0_; OACC[d_][1] *= a1_;                                   \
        OACC[d_][2] *= a2_; OACC[d_][3] *= a3_;                                   \
      }                                                                           \
      LACC[0] *= a0_; LACC[1] *= a1_; LACC[2] *= a2_; LACC[3] *= a3_;             \
      MR = mn_;                                                                   \
    }                                                                             \
    const float mnc_ = MR * C;                                                    \
    u16x4 pw_;                                                                    \
    _Pragma("unroll") for (int r4 = 0; r4 < 4; r4++)                              \
      pw_[r4] = f2bf(__builtin_amdgcn_exp2f(__builtin_fmaf(S0[r4], C, -mnc_)));   \
    *(u16x4*)&Pw[l15 * 64 + (( 0 + 4 * l4) ^ sw)] = pw_;                          \
    _Pragma("unroll") for (int r4 = 0; r4 < 4; r4++)                              \
      pw_[r4] = f2bf(__builtin_amdgcn_exp2f(__builtin_fmaf(S1[r4], C, -mnc_)));   \
    *(u16x4*)&Pw[l15 * 64 + ((16 + 4 * l4) ^ sw)] = pw_;                          \
    _Pragma("unroll") for (int r4 = 0; r4 < 4; r4++)                              \
      pw_[r4] = f2bf(__builtin_amdgcn_exp2f(__builtin_fmaf(S2[r4], C, -mnc_)));   \
    *(u16x4*)&Pw[l15 * 64 + ((32 + 4 * l4) ^ sw)] = pw_;                          \
    _Pragma("unroll") for (int r4 = 0; r4 < 4; r4++)                              \
      pw_[r4] = f2bf(__builtin_amdgcn_exp2f(__builtin_fmaf(S3[r4], C, -mnc_)));   \
    *(u16x4*)&Pw[l15 * 64 + ((48 + 4 * l4) ^ sw)] = pw_;                          \
    PF0 = *(const bf16x8*)&Pw[l15 * 64 + ((8 * l4) ^ sw)];                        \
    PF1 = *(const bf16x8*)&Pw[l15 * 64 + ((32 + 8 * l4) ^ sw)];                   \
  }

#define PV2(DI)                                                                   \
  {                                                                               \
    const int dd_ = (DI) * 16 + l15;                                              \
    const int vm_ = 8 * ((dd_ ^ (dd_ >> 3)) & 7);                                 \
    const bf16x8 v0_ = *(const bf16x8*)&Vtc[dd_ * 64 + ((8 * l4) ^ vm_)];         \
    const bf16x8 v1_ = *(const bf16x8*)&Vtc[dd_ * 64 + ((32 + 8 * l4) ^ vm_)];    \
    oA[DI] = MFMA16(pA0, v0_, oA[DI]);                                            \
    oA[DI] = MFMA16(pA1, v1_, oA[DI]);                                            \
    oB[DI] = MFMA16(pB0, v0_, oB[DI]);                                            \
    oB[DI] = MFMA16(pB1, v1_, oB[DI]);                                            \
  }

#define PV1(DI)                                                                   \
  {                                                                               \
    const int dd_ = (DI) * 16 + l15;                                              \
    const int vm_ = 8 * ((dd_ ^ (dd_ >> 3)) & 7);                                 \
    const bf16x8 v0_ = *(const bf16x8*)&Vtc[dd_ * 64 + ((8 * l4) ^ vm_)];         \
    const bf16x8 v1_ = *(const bf16x8*)&Vtc[dd_ * 64 + ((32 + 8 * l4) ^ vm_)];    \
    oB[DI] = MFMA16(pB0, v0_, oB[DI]);                                            \
    oB[DI] = MFMA16(pB1, v1_, oB[DI]);                                            \
  }

__global__ __launch_bounds__(256, 4) void attn_kernel(const unsigned short* __restrict__ Qb,
                                                      const unsigned short* __restrict__ Kb,
                                                      const unsigned short* __restrict__ Vb,
                                                      unsigned short* __restrict__ Ob) {
  const int bid = blockIdx.x;
  const int xcd = bid & 7, slot = bid >> 3;       // round-robin dispatch: bid%8 = XCD
  const int hb = xcd * 8 + (slot >> 4);           // 8 (h,b) groups per XCD
  const int p = slot & 15;
  const int h = hb & 15, bb = hb >> 4;

  const int tid = threadIdx.x, w = tid >> 6, lane = tid & 63, l15 = lane & 15, l4 = lane >> 4;

  __shared__ unsigned short K_lds[2][64 * 64];    // [buf][kv][d], col-swizzled
  __shared__ unsigned short Vt_lds[2][64 * 64];   // [buf][d][kv], col-swizzled
  __shared__ unsigned short P_lds[4][16 * 64];    // per-wave [q][kv], col-swizzled

  const size_t brow = (size_t)bb * 2048;
  const int qq = w * 16 + l15;                    // in-tile q row (diag mask)
  const int sw = 8 * (l15 & 7);                   // K/P read swizzle (row&7 == l15&7)
  constexpr float C = 0.18033688f;                // 0.125 * log2(e)
  const bf16x8 ones = {0x3F80, 0x3F80, 0x3F80, 0x3F80, 0x3F80, 0x3F80, 0x3F80, 0x3F80};
  unsigned short* Pw = &P_lds[w][0];

  const int qbA = p, qbB = 31 - p;
  const int lastB = qbB;

  bf16x8 qfA0, qfA1, qfB0, qfB1;
  {
    const unsigned short* qa = Qb + (brow + qbA * 64 + qq) * 1024 + h * 64 + 8 * l4;
    qfA0 = *(const bf16x8*)qa;
    qfA1 = *(const bf16x8*)(qa + 32);
    const unsigned short* qbp = Qb + (brow + qbB * 64 + qq) * 1024 + h * 64 + 8 * l4;
    qfB0 = *(const bf16x8*)qbp;
    qfB1 = *(const bf16x8*)(qbp + 32);
  }

  f32x4 oA[4] = {}, oB[4] = {};
  f32x4 lA4 = {0.f, 0.f, 0.f, 0.f}, lB4 = {0.f, 0.f, 0.f, 0.f};
  float mrA = -__builtin_inff(), mrB = -__builtin_inff();

  // K staging: DMA with pre-swizzled global source (m173 pattern).
  const int kcol = 8 * ((lane & 7) ^ ((lane >> 3) & 7));
  const unsigned short* gk = Kb + (brow + 8 * w + (lane >> 3)) * 1024 + h * 64 + kcol;
  // V staging: each thread loads kv rows (vr0, vr0+1), d-chunk vsc..+7.
  const int vr0 = 2 * (tid >> 3);                 // 0..62
  const int vsc = (tid & 7) * 8;
  const unsigned short* gv = Vb + (brow + vr0) * 1024 + h * 64 + vsc;

  auto vt_write = [&](int buf, const bf16x8& v0, const bf16x8& v1) {
#pragma unroll
    for (int j = 0; j < 8; j++) {
      const int d = vsc + j;
      const int msk = 8 * ((d ^ (d >> 3)) & 7);
      uint32_t pk = (uint32_t)(unsigned short)v0[j] |
                    ((uint32_t)(unsigned short)v1[j] << 16);
      *(uint32_t*)&Vt_lds[buf][d * 64 + (vr0 ^ msk)] = pk;
    }
  };

  // ---- prologue: stage tile 0 into buf 0 ----
  gload16(gk, (char*)K_lds[0] + w * 1024);
  gload16(gk + 32 * 1024, (char*)K_lds[0] + w * 1024 + 4096);
  {
    bf16x8 v0 = *(const bf16x8*)gv;
    bf16x8 v1 = *(const bf16x8*)(gv + 1024);
    vt_write(0, v0, v1);
  }
  __syncthreads();

  // ---- main loop: one barrier per KV tile ----
  for (int kb = 0; kb <= lastB; ++kb) {
    const int cur = kb & 1, nxt = cur ^ 1;
    const bool pre = kb < lastB;
    const unsigned short* Kc = K_lds[cur];
    const unsigned short* Vtc = Vt_lds[cur];
    bf16x8 pv0, pv1;
    if (pre) {
      const size_t off = (size_t)(kb + 1) * 64 * 1024;
      gload16(gk + off, (char*)K_lds[nxt] + w * 1024);
      gload16(gk + off + 32 * 1024, (char*)K_lds[nxt] + w * 1024 + 4096);
      pv0 = *(const bf16x8*)(gv + off);
      pv1 = *(const bf16x8*)(gv + off + 1024);
    }

    if (kb <= qbA) {
      // ---- stream A: QK + softmax (sA dies here) ----
      bf16x8 pA0, pA1;
      {
        f32x4 sA0, sA1, sA2, sA3;
        __builtin_amdgcn_s_setprio(1);
        QK_S(0, qfA0, qfA1, sA0)
        QK_S(1, qfA0, qfA1, sA1)
        QK_S(2, qfA0, qfA1, sA2)
        QK_S(3, qfA0, qfA1, sA3)
        __builtin_amdgcn_s_setprio(0);
        const bool diagA = (kb == qbA);
        SMAX(sA0, sA1, sA2, sA3, mrA, oA, lA4, diagA, pA0, pA1)
      }
      // ---- stream B: QK + softmax (sB dies here; pA co-live, +8 regs only) ----
      bf16x8 pB0, pB1;
      {
        f32x4 sB0, sB1, sB2, sB3;
        __builtin_amdgcn_s_setprio(1);
        QK_S(0, qfB0, qfB1, sB0)
        QK_S(1, qfB0, qfB1, sB1)
        QK_S(2, qfB0, qfB1, sB2)
        QK_S(3, qfB0, qfB1, sB3)
        __builtin_amdgcn_s_setprio(0);
        SMAX(sB0, sB1, sB2, sB3, mrB, oB, lB4, false, pB0, pB1)
      }
      // ---- fused PV: each V frag read once, feeds both streams ----
      __builtin_amdgcn_s_setprio(1);
      PV2(0) PV2(1) PV2(2) PV2(3)
      lA4 = MFMA16(pA0, ones, lA4);
      lA4 = MFMA16(pA1, ones, lA4);
      lB4 = MFMA16(pB0, ones, lB4);
      lB4 = MFMA16(pB1, ones, lB4);
      __builtin_amdgcn_s_setprio(0);
    } else {
      // ---- single stream (B), R5-equivalent ----
      bf16x8 pB0, pB1;
      {
        f32x4 sB0, sB1, sB2, sB3;
        __builtin_amdgcn_s_setprio(1);
        QK_S(0, qfB0, qfB1, sB0)
        QK_S(1, qfB0, qfB1, sB1)
        QK_S(2, qfB0, qfB1, sB2)
        QK_S(3, qfB0, qfB1, sB3)
        __builtin_amdgcn_s_setprio(0);
        const bool diagB = (kb == lastB);
        SMAX(sB0, sB1, sB2, sB3, mrB, oB, lB4, diagB, pB0, pB1)
      }
      __builtin_amdgcn_s_setprio(1);
      PV1(0) PV1(1) PV1(2) PV1(3)
      lB4 = MFMA16(pB0, ones, lB4);
      lB4 = MFMA16(pB1, ones, lB4);
      __builtin_amdgcn_s_setprio(0);
    }

    if (pre) vt_write(nxt, pv0, pv1);
    __syncthreads();
  }

  // ---- epilogue: normalize + store both q-tiles (l rows == O rows, no shfl) ----
  {
    const float li[4] = {1.0f / lA4[0], 1.0f / lA4[1], 1.0f / lA4[2], 1.0f / lA4[3]};
#pragma unroll
    for (int d = 0; d < 4; ++d)
#pragma unroll
      for (int r4 = 0; r4 < 4; r4++) {
        const size_t orow = brow + qbA * 64 + w * 16 + 4 * l4 + r4;
        Ob[orow * 1024 + h * 64 + d * 16 + l15] = f2bf(oA[d][r4] * li[r4]);
      }
  }
  {
    const float li[4] = {1.0f / lB4[0], 1.0f / lB4[1], 1.0f / lB4[2], 1.0f / lB4[3]};
#pragma unroll
    for (int d = 0; d < 4; ++d)
#pragma unroll
      for (int r4 = 0; r4 < 4; r4++) {
        const size_t orow = brow + qbB * 64 + w * 16 + 4 * l4 + r4;
        Ob[orow * 1024 + h * 64 + d * 16 + l15] = f2bf(oB[d][r4] * li[r4]);
      }
  }
}

// ---------- launch ----------
extern "C" void kernel_launch(void* const* d_in, const int* in_sizes, int n_in,
                              void* d_out, int out_size, void* d_ws, size_t ws_size,
                              hipStream_t stream) {
  const float* x  = (const float*)d_in[0];
  const float* wq = (const float*)d_in[1];
  const float* wk = (const float*)d_in[2];
  const float* wv = (const float*)d_in[3];
  const float* wo = (const float*)d_in[4];

  char* ws = (char*)d_ws;
  // layout (bytes): Xb 16MB | Wt 4x2MB | Q 16MB | K 16MB | V 16MB ; O aliases Xb
  unsigned short* Xb  = (unsigned short*)(ws);
  unsigned short* Wt  = (unsigned short*)(ws + (16u << 20));
  unsigned short* Wqt = Wt;
  unsigned short* Wkt = Wt + (1u << 20);
  unsigned short* Wvt = Wt + (2u << 20);
  unsigned short* Wot = Wt + (3u << 20);
  unsigned short* Qb  = (unsigned short*)(ws + (24u << 20));
  unsigned short* Kb  = (unsigned short*)(ws + (40u << 20));
  unsigned short* Vb  = (unsigned short*)(ws + (56u << 20));
  unsigned short* Ob  = Xb;   // X no longer needed after QKV projection

  cvt_x_kernel<<<8192, 256, 0, stream>>>(x, Xb);                       // 8192*1024 f32 -> bf16
  wt_cvt_kernel<<<dim3(32, 32, 4), 256, 0, stream>>>(wq, wk, wv, wo, Wt);
  gemm128_kernel<false><<<dim3(64, 8, 3), 256, 0, stream>>>(Xb, Wqt, Wkt, Wvt, Qb, Kb, Vb);
  attn_kernel<<<1024, 256, 0, stream>>>(Qb, Kb, Vb, Ob);
  gemm64_kernel<<<dim3(128, 8), 256, 0, stream>>>(Ob, Wot, (float*)d_out);
}

// Round 11
// 174.281 us; speedup vs baseline: 2.9362x; 2.9362x over previous
//
#include <hip/hip_runtime.h>
#include <hip/hip_bf16.h>
#include <stdint.h>

// ---------- types ----------
typedef __attribute__((ext_vector_type(8))) short bf16x8;     // 8 bf16 (4 VGPRs) MFMA frag
typedef __attribute__((ext_vector_type(4))) float f32x4;      // MFMA accum
typedef __attribute__((ext_vector_type(4))) unsigned short u16x4;
typedef __attribute__((ext_vector_type(4))) float float4v;

#define MFMA16(a, b, c) __builtin_amdgcn_mfma_f32_16x16x32_bf16((a), (b), (c), 0, 0, 0)

// Native f32->bf16 (RTNE); pairs lower to v_cvt_pk_bf16_f32 on gfx950.
__device__ __forceinline__ unsigned short f2bf(float f) {
  return __builtin_bit_cast(unsigned short, (__bf16)f);
}
__device__ __forceinline__ float m3(float a, float b, float c) {
  return fmaxf(fmaxf(a, b), c);                 // clang fuses to v_max3_f32
}

typedef const __attribute__((address_space(1))) void* gptr1_t;
typedef __attribute__((address_space(3))) void* lptr3_t;
__device__ __forceinline__ void gload16(const void* g, void* l) {
  // HW semantics: LDS dest = wave-uniform base + lane*16; global src per-lane.
  __builtin_amdgcn_global_load_lds((gptr1_t)g, (lptr3_t)l, 16, 0, 0);
}

// ---------- 1) x fp32 -> bf16 ----------
__global__ __launch_bounds__(256) void cvt_x_kernel(const float* __restrict__ in,
                                                    unsigned short* __restrict__ out) {
  int i = blockIdx.x * 256 + threadIdx.x;          // exactly n/4 threads launched
  float4v f = ((const float4v*)in)[i];
  u16x4 o;
  o[0] = f2bf(f[0]); o[1] = f2bf(f[1]); o[2] = f2bf(f[2]); o[3] = f2bf(f[3]);
  ((u16x4*)out)[i] = o;
}

// ---------- 2) weight fp32 [K][N] -> bf16 transposed [N][K] ----------
__global__ __launch_bounds__(256) void wt_cvt_kernel(const float* __restrict__ w0,
                                                     const float* __restrict__ w1,
                                                     const float* __restrict__ w2,
                                                     const float* __restrict__ w3,
                                                     unsigned short* __restrict__ out) {
  const float* in = blockIdx.z == 0 ? w0 : blockIdx.z == 1 ? w1 : blockIdx.z == 2 ? w2 : w3;
  unsigned short* o = out + (size_t)blockIdx.z * 1024 * 1024;
  __shared__ float tile[32][33];
  int tx = threadIdx.x & 31, ty = threadIdx.x >> 5;          // 32 x 8
  int c0 = blockIdx.x * 32, r0 = blockIdx.y * 32;
#pragma unroll
  for (int i = 0; i < 4; i++)
    tile[ty + 8 * i][tx] = in[(size_t)(r0 + ty + 8 * i) * 1024 + c0 + tx];
  __syncthreads();
#pragma unroll
  for (int i = 0; i < 4; i++)
    o[(size_t)(c0 + ty + 8 * i) * 1024 + r0 + tx] = f2bf(tile[tx][ty + 8 * i]);
}

// ---------- 3) GEMM 128x128, BK=32 (m97 structure): C = A[M][1024](bf16) @ W ----------
template <bool OUTF32>
__global__ __launch_bounds__(256) void gemm128_kernel(
    const unsigned short* __restrict__ A,
    const unsigned short* __restrict__ B0, const unsigned short* __restrict__ B1,
    const unsigned short* __restrict__ B2,
    void* C0, void* C1, void* C2) {
  constexpr int K = 1024, N = 1024;
  const unsigned short* Bt = blockIdx.z == 0 ? B0 : blockIdx.z == 1 ? B1 : B2;
  void* Cv = blockIdx.z == 0 ? C0 : blockIdx.z == 1 ? C1 : C2;

  __shared__ unsigned short As[128 * 32];
  __shared__ unsigned short Bs[128 * 32];

  const int tid = threadIdx.x;
  const int w = tid >> 6, lane = tid & 63, l15 = lane & 15, l4 = lane >> 4;
  const int wm = w >> 1, wn = w & 1;
  const int m0 = blockIdx.x * 128, n0 = blockIdx.y * 128;

  f32x4 acc[4][4] = {};

  const int srow = w * 32 + (lane >> 2);     // staging row (inst i adds 16)
  const int scol = (lane & 3) * 8;           // bf16 col within BK
  const unsigned short* ga = A + (size_t)(m0 + srow) * K + scol;
  const unsigned short* gb = Bt + (size_t)(n0 + srow) * K + scol;
  char* lA = (char*)As + w * 2048;           // + i*1024 ; HW adds lane*16
  char* lB = (char*)Bs + w * 2048;

  for (int k0 = 0; k0 < K; k0 += 32) {
    __syncthreads();
    gload16(ga + k0, lA);
    gload16(ga + k0 + 16 * K, lA + 1024);
    gload16(gb + k0, lB);
    gload16(gb + k0 + 16 * K, lB + 1024);
    __syncthreads();

    bf16x8 af[4], bfr[4];
#pragma unroll
    for (int mi = 0; mi < 4; mi++)
      af[mi] = *(const bf16x8*)&As[(wm * 64 + mi * 16 + l15) * 32 + 8 * l4];
#pragma unroll
    for (int ni = 0; ni < 4; ni++)
      bfr[ni] = *(const bf16x8*)&Bs[(wn * 64 + ni * 16 + l15) * 32 + 8 * l4];
#pragma unroll
    for (int mi = 0; mi < 4; mi++)
#pragma unroll
      for (int ni = 0; ni < 4; ni++)
        acc[mi][ni] = MFMA16(af[mi], bfr[ni], acc[mi][ni]);
  }

#pragma unroll
  for (int mi = 0; mi < 4; mi++)
#pragma unroll
    for (int ni = 0; ni < 4; ni++)
#pragma unroll
      for (int r = 0; r < 4; r++) {
        int mg = m0 + wm * 64 + mi * 16 + 4 * l4 + r;
        int ng = n0 + wn * 64 + ni * 16 + l15;
        if (OUTF32)
          ((float*)Cv)[(size_t)mg * N + ng] = acc[mi][ni][r];
        else
          ((unsigned short*)Cv)[(size_t)mg * N + ng] = f2bf(acc[mi][ni][r]);
      }
}

// ---------- 3b) GEMM 64x128 f32-out: out-projection (1024 blocks = 4/CU) ----------
__global__ __launch_bounds__(256) void gemm64_kernel(const unsigned short* __restrict__ A,
                                                     const unsigned short* __restrict__ Bt,
                                                     float* __restrict__ Cv) {
  constexpr int K = 1024, N = 1024;
  __shared__ unsigned short As[64 * 32];
  __shared__ unsigned short Bs[128 * 32];

  const int tid = threadIdx.x;
  const int w = tid >> 6, lane = tid & 63, l15 = lane & 15, l4 = lane >> 4;
  const int wm = w >> 1, wn = w & 1;                // wave tile 32x64
  const int m0 = blockIdx.x * 64, n0 = blockIdx.y * 128;

  f32x4 acc[2][4] = {};

  const int arow = w * 16 + (lane >> 2);            // A staging: 16 rows/wave
  const int brow = w * 32 + (lane >> 2);            // B staging: 32 rows/wave (2 insts)
  const int scol = (lane & 3) * 8;
  const unsigned short* ga = A + (size_t)(m0 + arow) * K + scol;
  const unsigned short* gb = Bt + (size_t)(n0 + brow) * K + scol;
  char* lA = (char*)As + w * 1024;
  char* lB = (char*)Bs + w * 2048;

  for (int k0 = 0; k0 < K; k0 += 32) {
    __syncthreads();
    gload16(ga + k0, lA);
    gload16(gb + k0, lB);
    gload16(gb + k0 + 16 * K, lB + 1024);
    __syncthreads();

    bf16x8 af[2], bfr[4];
#pragma unroll
    for (int mi = 0; mi < 2; mi++)
      af[mi] = *(const bf16x8*)&As[(wm * 32 + mi * 16 + l15) * 32 + 8 * l4];
#pragma unroll
    for (int ni = 0; ni < 4; ni++)
      bfr[ni] = *(const bf16x8*)&Bs[(wn * 64 + ni * 16 + l15) * 32 + 8 * l4];
#pragma unroll
    for (int mi = 0; mi < 2; mi++)
#pragma unroll
      for (int ni = 0; ni < 4; ni++)
        acc[mi][ni] = MFMA16(af[mi], bfr[ni], acc[mi][ni]);
  }

#pragma unroll
  for (int mi = 0; mi < 2; mi++)
#pragma unroll
    for (int ni = 0; ni < 4; ni++)
#pragma unroll
      for (int r = 0; r < 4; r++) {
        int mg = m0 + wm * 32 + mi * 16 + 4 * l4 + r;
        int ng = n0 + wn * 64 + ni * 16 + l15;
        Cv[(size_t)mg * N + ng] = acc[mi][ni][r];
      }
}

// ---------- 4) causal flash attention ----------
// R5 verified structure (76us attn, no spill). Key invariant learned over
// R4/R6/R7/R8/R10 (five spill failures): each q-stream must complete its
// QK -> softmax -> PV atomically; carrying any P fragment across the other
// stream's softmax phase (divergent defer-max branch) triggers catastrophic
// scratch spill regardless of source form (arrays, macros, named scalars).
// Structure: flat grid 1024 XCD-chunked (same-KV blocks -> same XCD L2, KV
// L2-resident); paired q-tiles qbA=p / qbB=31-p (uniform 33 tiles/block);
// double-buffered K/Vt; ONE barrier per KV tile; K via global_load_lds with
// pre-swizzled global src; V reg-staged; ones-MFMA l-sum (l rows == O rows);
// defer-max (T13); max3-tree row max; exp2-domain softmax.
__global__ __launch_bounds__(256, 4) void attn_kernel(const unsigned short* __restrict__ Qb,
                                                      const unsigned short* __restrict__ Kb,
                                                      const unsigned short* __restrict__ Vb,
                                                      unsigned short* __restrict__ Ob) {
  const int bid = blockIdx.x;
  const int xcd = bid & 7, slot = bid >> 3;       // round-robin dispatch: bid%8 = XCD
  const int hb = xcd * 8 + (slot >> 4);           // 8 (h,b) groups per XCD
  const int p = slot & 15;
  const int h = hb & 15, bb = hb >> 4;

  const int tid = threadIdx.x, w = tid >> 6, lane = tid & 63, l15 = lane & 15, l4 = lane >> 4;

  __shared__ unsigned short K_lds[2][64 * 64];    // [buf][kv][d], col-swizzled
  __shared__ unsigned short Vt_lds[2][64 * 64];   // [buf][d][kv], col-swizzled
  __shared__ unsigned short P_lds[4][16 * 64];    // per-wave [q][kv], col-swizzled

  const size_t brow = (size_t)bb * 2048;
  const int qq = w * 16 + l15;                    // in-tile q row (diag mask)
  const int sw = 8 * (l15 & 7);                   // K/P read swizzle (row&7 == l15&7)
  constexpr float C = 0.18033688f;                // 0.125 * log2(e)
  const bf16x8 ones = {0x3F80, 0x3F80, 0x3F80, 0x3F80, 0x3F80, 0x3F80, 0x3F80, 0x3F80};

  const int qbA = p, qbB = 31 - p;
  const int lastB = qbB;

  bf16x8 qfA0, qfA1, qfB0, qfB1;
  {
    const unsigned short* qa = Qb + (brow + qbA * 64 + qq) * 1024 + h * 64 + 8 * l4;
    qfA0 = *(const bf16x8*)qa;
    qfA1 = *(const bf16x8*)(qa + 32);
    const unsigned short* qbp = Qb + (brow + qbB * 64 + qq) * 1024 + h * 64 + 8 * l4;
    qfB0 = *(const bf16x8*)qbp;
    qfB1 = *(const bf16x8*)(qbp + 32);
  }

  f32x4 oA[4] = {}, oB[4] = {};
  f32x4 lA4 = {0.f, 0.f, 0.f, 0.f}, lB4 = {0.f, 0.f, 0.f, 0.f};
  float mrA = -__builtin_inff(), mrB = -__builtin_inff();

  // K staging: DMA with pre-swizzled global source (m173 pattern).
  const int kcol = 8 * ((lane & 7) ^ ((lane >> 3) & 7));
  const unsigned short* gk = Kb + (brow + 8 * w + (lane >> 3)) * 1024 + h * 64 + kcol;
  // V staging: each thread loads kv rows (vr0, vr0+1), d-chunk vsc..+7.
  const int vr0 = 2 * (tid >> 3);                 // 0..62
  const int vsc = (tid & 7) * 8;
  const unsigned short* gv = Vb + (brow + vr0) * 1024 + h * 64 + vsc;

  auto vt_write = [&](int buf, const bf16x8& v0, const bf16x8& v1) {
#pragma unroll
    for (int j = 0; j < 8; j++) {
      const int d = vsc + j;
      const int msk = 8 * ((d ^ (d >> 3)) & 7);
      uint32_t pk = (uint32_t)(unsigned short)v0[j] |
                    ((uint32_t)(unsigned short)v1[j] << 16);
      *(uint32_t*)&Vt_lds[buf][d * 64 + (vr0 ^ msk)] = pk;
    }
  };

  auto tile_compute = [&](const unsigned short* Kc, const unsigned short* Vtc,
                          const bf16x8& q0f, const bf16x8& q1f, f32x4* oacc,
                          float& m_run, f32x4& lacc, bool diag) {
    // S^T = K x Q^T : 8 MFMA
    f32x4 s[4];
    __builtin_amdgcn_s_setprio(1);
#pragma unroll
    for (int sub = 0; sub < 4; ++sub) {
      const unsigned short* kr0 = &Kc[(sub * 16 + l15) * 64 + ((8 * l4) ^ sw)];
      const unsigned short* kr1 = &Kc[(sub * 16 + l15) * 64 + ((32 + 8 * l4) ^ sw)];
      f32x4 z = {0.f, 0.f, 0.f, 0.f};
      z = MFMA16(*(const bf16x8*)kr0, q0f, z);
      z = MFMA16(*(const bf16x8*)kr1, q1f, z);
      s[sub] = z;
    }
    __builtin_amdgcn_s_setprio(0);

    // causal mask only on the diagonal tile
    if (diag) {
#pragma unroll
      for (int sub = 0; sub < 4; ++sub)
#pragma unroll
        for (int r4 = 0; r4 < 4; r4++) {
          const int kv_t = sub * 16 + 4 * l4 + r4;
          s[sub][r4] = (kv_t > qq) ? -__builtin_inff() : s[sub][r4];
        }
    }
    // max3-tree reduce (16 -> 6 -> 2 -> 1), then cross-lane over l4 groups
    const float t0 = m3(s[0][0], s[0][1], s[0][2]);
    const float t1 = m3(s[0][3], s[1][0], s[1][1]);
    const float t2 = m3(s[1][2], s[1][3], s[2][0]);
    const float t3 = m3(s[2][1], s[2][2], s[2][3]);
    const float t4 = m3(s[3][0], s[3][1], s[3][2]);
    float mt = fmaxf(m3(t0, t1, t2), m3(t3, t4, s[3][3]));
    mt = fmaxf(mt, __shfl_xor(mt, 16));
    mt = fmaxf(mt, __shfl_xor(mt, 32));

    // defer-max: only rescale when some row grew by > 8 (log2 units) => P <= 2^8
    if (!__all(mt <= m_run + 44.3614f)) {         // 44.3614 = 8 / C
      const float m_new = fmaxf(m_run, mt);
      const float alpha = __builtin_amdgcn_exp2f((m_run - m_new) * C);
      const float ao0 = __shfl(alpha, 4 * l4 + 0);
      const float ao1 = __shfl(alpha, 4 * l4 + 1);
      const float ao2 = __shfl(alpha, 4 * l4 + 2);
      const float ao3 = __shfl(alpha, 4 * l4 + 3);
#pragma unroll
      for (int d = 0; d < 4; ++d) {
        oacc[d][0] *= ao0; oacc[d][1] *= ao1; oacc[d][2] *= ao2; oacc[d][3] *= ao3;
      }
      lacc[0] *= ao0; lacc[1] *= ao1; lacc[2] *= ao2; lacc[3] *= ao3;
      m_run = m_new;
    }
    const float mnc = m_run * C;

#pragma unroll
    for (int sub = 0; sub < 4; ++sub) {
      u16x4 pw;
#pragma unroll
      for (int r4 = 0; r4 < 4; r4++)
        pw[r4] = f2bf(__builtin_amdgcn_exp2f(__builtin_fmaf(s[sub][r4], C, -mnc)));
      *(u16x4*)&P_lds[w][l15 * 64 + ((sub * 16 + 4 * l4) ^ sw)] = pw;
    }

    // PV: O[q][d] += P[q][kv] V[kv][d]; l[q] += sum_kv P[q][kv] via ones-MFMA
    const bf16x8 pf0 = *(const bf16x8*)&P_lds[w][l15 * 64 + ((8 * l4) ^ sw)];
    const bf16x8 pf1 = *(const bf16x8*)&P_lds[w][l15 * 64 + ((32 + 8 * l4) ^ sw)];
    __builtin_amdgcn_s_setprio(1);
#pragma unroll
    for (int d = 0; d < 4; ++d) {
      const int dd = d * 16 + l15;
      const int vm = 8 * ((dd ^ (dd >> 3)) & 7);
      const unsigned short* vp0 = &Vtc[dd * 64 + ((8 * l4) ^ vm)];
      const unsigned short* vp1 = &Vtc[dd * 64 + ((32 + 8 * l4) ^ vm)];
      oacc[d] = MFMA16(pf0, *(const bf16x8*)vp0, oacc[d]);
      oacc[d] = MFMA16(pf1, *(const bf16x8*)vp1, oacc[d]);
    }
    lacc = MFMA16(pf0, ones, lacc);
    lacc = MFMA16(pf1, ones, lacc);
    __builtin_amdgcn_s_setprio(0);
  };

  // ---- prologue: stage tile 0 into buf 0 ----
  gload16(gk, (char*)K_lds[0] + w * 1024);
  gload16(gk + 32 * 1024, (char*)K_lds[0] + w * 1024 + 4096);
  {
    bf16x8 v0 = *(const bf16x8*)gv;
    bf16x8 v1 = *(const bf16x8*)(gv + 1024);
    vt_write(0, v0, v1);
  }
  __syncthreads();

  // ---- main loop: one barrier per KV tile ----
  for (int kb = 0; kb <= lastB; ++kb) {
    const int cur = kb & 1, nxt = cur ^ 1;
    const bool pre = kb < lastB;
    bf16x8 pv0, pv1;
    if (pre) {
      const size_t off = (size_t)(kb + 1) * 64 * 1024;
      gload16(gk + off, (char*)K_lds[nxt] + w * 1024);
      gload16(gk + off + 32 * 1024, (char*)K_lds[nxt] + w * 1024 + 4096);
      pv0 = *(const bf16x8*)(gv + off);
      pv1 = *(const bf16x8*)(gv + off + 1024);
    }

    if (kb <= qbA)
      tile_compute(K_lds[cur], Vt_lds[cur], qfA0, qfA1, oA, mrA, lA4, kb == qbA);
    tile_compute(K_lds[cur], Vt_lds[cur], qfB0, qfB1, oB, mrB, lB4, kb == lastB);

    if (pre) vt_write(nxt, pv0, pv1);
    __syncthreads();
  }

  // ---- epilogue: normalize + store both q-tiles (l rows == O rows, no shfl) ----
  {
    const float li[4] = {1.0f / lA4[0], 1.0f / lA4[1], 1.0f / lA4[2], 1.0f / lA4[3]};
#pragma unroll
    for (int d = 0; d < 4; ++d)
#pragma unroll
      for (int r4 = 0; r4 < 4; r4++) {
        const size_t orow = brow + qbA * 64 + w * 16 + 4 * l4 + r4;
        Ob[orow * 1024 + h * 64 + d * 16 + l15] = f2bf(oA[d][r4] * li[r4]);
      }
  }
  {
    const float li[4] = {1.0f / lB4[0], 1.0f / lB4[1], 1.0f / lB4[2], 1.0f / lB4[3]};
#pragma unroll
    for (int d = 0; d < 4; ++d)
#pragma unroll
      for (int r4 = 0; r4 < 4; r4++) {
        const size_t orow = brow + qbB * 64 + w * 16 + 4 * l4 + r4;
        Ob[orow * 1024 + h * 64 + d * 16 + l15] = f2bf(oB[d][r4] * li[r4]);
      }
  }
}

// ---------- launch ----------
extern "C" void kernel_launch(void* const* d_in, const int* in_sizes, int n_in,
                              void* d_out, int out_size, void* d_ws, size_t ws_size,
                              hipStream_t stream) {
  const float* x  = (const float*)d_in[0];
  const float* wq = (const float*)d_in[1];
  const float* wk = (const float*)d_in[2];
  const float* wv = (const float*)d_in[3];
  const float* wo = (const float*)d_in[4];

  char* ws = (char*)d_ws;
  // layout (bytes): Xb 16MB | Wt 4x2MB | Q 16MB | K 16MB | V 16MB ; O aliases Xb
  unsigned short* Xb  = (unsigned short*)(ws);
  unsigned short* Wt  = (unsigned short*)(ws + (16u << 20));
  unsigned short* Wqt = Wt;
  unsigned short* Wkt = Wt + (1u << 20);
  unsigned short* Wvt = Wt + (2u << 20);
  unsigned short* Wot = Wt + (3u << 20);
  unsigned short* Qb  = (unsigned short*)(ws + (24u << 20));
  unsigned short* Kb  = (unsigned short*)(ws + (40u << 20));
  unsigned short* Vb  = (unsigned short*)(ws + (56u << 20));
  unsigned short* Ob  = Xb;   // X no longer needed after QKV projection

  cvt_x_kernel<<<8192, 256, 0, stream>>>(x, Xb);                       // 8192*1024 f32 -> bf16
  wt_cvt_kernel<<<dim3(32, 32, 4), 256, 0, stream>>>(wq, wk, wv, wo, Wt);
  gemm128_kernel<false><<<dim3(64, 8, 3), 256, 0, stream>>>(Xb, Wqt, Wkt, Wvt, Qb, Kb, Vb);
  attn_kernel<<<1024, 256, 0, stream>>>(Qb, Kb, Vb, Ob);
  gemm64_kernel<<<dim3(128, 8), 256, 0, stream>>>(Ob, Wot, (float*)d_out);
}